// Round 3
// baseline (468.401 us; speedup 1.0000x reference)
//
#include <hip/hip_runtime.h>
#include <hip/hip_bf16.h>

// ---------------- problem constants ----------------
constexpr int NN = 50000;     // nodes
constexpr int NE = 400000;    // edges (without self loops)
constexpr int NE2 = NE + NN;  // with self loops
constexpr float NEG_SLOPE = 0.2f;
constexpr float LOG2E = 1.44269504f;

typedef __attribute__((ext_vector_type(8))) __bf16 bf16x8;
typedef __attribute__((ext_vector_type(4))) float f32x4;
typedef __attribute__((ext_vector_type(2))) float f32x2;

__device__ inline float bf2f(unsigned short u) { return __uint_as_float(((unsigned)u) << 16); }
__device__ inline unsigned short f2bf(float f) {
    unsigned x = __float_as_uint(f);
    return (unsigned short)((x + 0x7fffu + ((x >> 16) & 1u)) >> 16);  // RNE
}
__device__ inline float bflo(unsigned u) { return __uint_as_float(u << 16); }
__device__ inline float bfhi(unsigned u) { return __uint_as_float(u & 0xffff0000u); }

__device__ inline void gload16(const unsigned short* g, unsigned short* l) {
    // async global->LDS, 16B per lane; LDS dest is wave-uniform base + lane*16
    __builtin_amdgcn_global_load_lds(
        (const __attribute__((address_space(1))) unsigned int*)(g),
        (__attribute__((address_space(3))) unsigned int*)(l), 16, 0, 0);
}

// ---------------- CSR build ----------------
__global__ void count_deg(const int* __restrict__ ei, int* __restrict__ deg) {
    int e = blockIdx.x * blockDim.x + threadIdx.x;
    if (e >= NE2) return;
    int dst = (e < NE) ? ei[NE + e] : (e - NE);
    atomicAdd(&deg[dst], 1);
}

// register-chunked single-block scan: 2 barriers total
__global__ __launch_bounds__(1024) void scan_deg(const int* __restrict__ deg,
                                                 int* __restrict__ row_ptr,
                                                 int* __restrict__ cursor) {
    constexpr int CH = (NN + 1023) / 1024;  // 49
    __shared__ int wsum[16];
    const int t = threadIdx.x, lane = t & 63, w = t >> 6;
    const int base = t * CH;
    int v[CH];
    int s = 0;
    #pragma unroll
    for (int i = 0; i < CH; ++i) {
        int idx = base + i;
        int dv = (idx < NN) ? deg[idx] : 0;
        v[i] = s;   // exclusive prefix within thread
        s += dv;
    }
    int x = s;
    #pragma unroll
    for (int off = 1; off < 64; off <<= 1) {
        int y = __shfl_up(x, off);
        if (lane >= off) x += y;
    }
    if (lane == 63) wsum[w] = x;
    __syncthreads();
    if (w == 0 && lane < 16) {
        int ss = wsum[lane];
        #pragma unroll
        for (int off = 1; off < 16; off <<= 1) {
            int y = __shfl_up(ss, off);
            if (lane >= off) ss += y;
        }
        wsum[lane] = ss;
    }
    __syncthreads();
    const int excl = ((w == 0) ? 0 : wsum[w - 1]) + (x - s);
    #pragma unroll
    for (int i = 0; i < CH; ++i) {
        int idx = base + i;
        if (idx < NN) { int e = excl + v[i]; row_ptr[idx] = e; cursor[idx] = e; }
    }
    if (t == 0) row_ptr[NN] = wsum[15];
}

__global__ void scatter_edges(const int* __restrict__ ei, int* __restrict__ cursor,
                              int* __restrict__ csr_src) {
    int e = blockIdx.x * blockDim.x + threadIdx.x;
    if (e >= NE2) return;
    int src, dst;
    if (e < NE) { src = ei[e]; dst = ei[NE + e]; }
    else        { src = dst = e - NE; }
    int pos = atomicAdd(&cursor[dst], 1);
    csr_src[pos] = src;
}

// ---------------- fp32 -> bf16 convert (x) ----------------
__global__ void f32_to_bf16(const float* __restrict__ in, unsigned short* __restrict__ out, int n4) {
    int i = blockIdx.x * blockDim.x + threadIdx.x;
    if (i >= n4) return;
    float4 v = *(const float4*)(in + 4 * (size_t)i);
    ushort4 o;
    o.x = f2bf(v.x); o.y = f2bf(v.y); o.z = f2bf(v.z); o.w = f2bf(v.w);
    *(ushort4*)(out + 4 * (size_t)i) = o;
}

// ---------------- one-shot weight conversion: all 8 W matrices -> bf16, concatenated ----------------
__global__ void conv_weights(const float* __restrict__ w0l, const float* __restrict__ w0r,
                             const float* __restrict__ w1l, const float* __restrict__ w1r,
                             const float* __restrict__ w2l, const float* __restrict__ w2r,
                             const float* __restrict__ w3l, const float* __restrict__ w3r,
                             unsigned short* __restrict__ out) {
    int i = blockIdx.x * blockDim.x + threadIdx.x;  // float4 index, 0..98303
    const float* src; int base;
    if      (i < 8192)  { src = w0l; base = 0; }
    else if (i < 16384) { src = w0r; base = 8192; }
    else if (i < 32768) { src = w1l; base = 16384; }
    else if (i < 49152) { src = w1r; base = 32768; }
    else if (i < 65536) { src = w2l; base = 49152; }
    else if (i < 81920) { src = w2r; base = 65536; }
    else if (i < 90112) { src = w3l; base = 81920; }
    else                { src = w3r; base = 90112; }
    float4 v = ((const float4*)src)[i - base];
    ushort4 o;
    o.x = f2bf(v.x); o.y = f2bf(v.y); o.z = f2bf(v.z); o.w = f2bf(v.w);
    ((ushort4*)out)[i] = o;
}

// ---------------- fused bf16 MFMA GEMM: [xl | xr] = A @ [Wl;Wr]^T + bias ----------------
// Double-buffered LDS, single barrier per K-step (T3 minimum 2-phase pipeline).
// Swapped MFMA operands -> lane holds 4 consecutive out-cols -> ushort4 stores.
#define GBM 128
#define GBN 128
#define GBK 64

__global__ __launch_bounds__(256) void gemm_fused(const unsigned short* __restrict__ A,
                                                  const unsigned short* __restrict__ Wc,
                                                  const float* __restrict__ bl,
                                                  const float* __restrict__ br,
                                                  unsigned short* __restrict__ outl,
                                                  unsigned short* __restrict__ outr,
                                                  int M, int Nhalf, int K, int lognx) {
    __shared__ __align__(16) unsigned short Alds[2][GBM * GBK];
    __shared__ __align__(16) unsigned short Wlds[2][GBN * GBK];
    // bijective XCD swizzle (m204): blocks sharing an A-tile land on the same XCD L2
    const int nwg = gridDim.x;
    const int q = nwg >> 3, r8 = nwg & 7;
    const int xcd = blockIdx.x & 7, off = blockIdx.x >> 3;
    const int wg = (xcd < r8 ? xcd * (q + 1) : r8 * (q + 1) + (xcd - r8) * q) + off;
    const int nx = 1 << lognx;
    const int bm = (wg >> lognx) * GBM, bn = (wg & (nx - 1)) * GBN;

    const int tid = threadIdx.x;
    const int lane = tid & 63, wave = tid >> 6;
    const int wr = wave >> 1, wc = wave & 1;       // wave -> 64x64 sub-tile
    const int lrow = lane & 15, kgrp = lane >> 4;  // fragment indices

    f32x4 acc[4][4] = {};

    auto stage = [&](int cur, int k0) {
        #pragma unroll
        for (int i = 0; i < 4; ++i) {
            int p = i * 256 + tid;            // chunk id
            int r = p >> 3, ck = p & 7;       // row, chunk-in-row
            int sck = ck ^ (r & 7);           // inverse-swizzled source chunk
            int ga = bm + r; ga = (ga < M) ? ga : (M - 1);   // clamp tail (write-guarded)
            gload16(A + (size_t)ga * K + k0 + sck * 8,
                    &Alds[cur][(unsigned)(i * 256 + wave * 64) * 8]);
            gload16(Wc + (size_t)(bn + r) * K + k0 + sck * 8,
                    &Wlds[cur][(unsigned)(i * 256 + wave * 64) * 8]);
        }
    };

    const int nt = K >> 6;
    stage(0, 0);
    __syncthreads();                // buf0 staged (vmcnt(0) inside)
    int cur = 0;
    for (int t = 0; t < nt; ++t) {
        if (t + 1 < nt) stage(cur ^ 1, (t + 1) * GBK);  // prefetch flies under MFMA
        const unsigned short* Ab = Alds[cur];
        const unsigned short* Wb = Wlds[cur];
        #pragma unroll
        for (int kk = 0; kk < GBK; kk += 32) {
            bf16x8 av[4], bv[4];
            #pragma unroll
            for (int i = 0; i < 4; ++i) {
                int ar = wr * 64 + i * 16 + lrow;
                int ch = ((kk >> 3) + kgrp) ^ (ar & 7);
                av[i] = *(const bf16x8*)(&Ab[ar * GBK + ch * 8]);
            }
            #pragma unroll
            for (int j = 0; j < 4; ++j) {
                int brw = wc * 64 + j * 16 + lrow;
                int ch = ((kk >> 3) + kgrp) ^ (brw & 7);
                bv[j] = *(const bf16x8*)(&Wb[brw * GBK + ch * 8]);
            }
            // swapped operands: D row-dim <- bv (out cols), col-dim <- av (out rows)
            #pragma unroll
            for (int i = 0; i < 4; ++i)
                #pragma unroll
                for (int j = 0; j < 4; ++j)
                    acc[i][j] = __builtin_amdgcn_mfma_f32_16x16x32_bf16(bv[j], av[i], acc[i][j], 0, 0, 0);
        }
        __syncthreads();            // drains next-stage vmcnt + protects buf reuse
        cur ^= 1;
    }

    // epilogue: lane holds out[row = bm+wr*64+i*16+lrow][col = cb+j*16+kgrp*4+r], r=0..3
    const int half = (bn >= Nhalf) ? 1 : 0;
    unsigned short* outp = half ? outr : outl;
    const float* bp = half ? br : bl;
    const int cb = bn - half * Nhalf + wc * 64;
    #pragma unroll
    for (int i = 0; i < 4; ++i) {
        int row = bm + wr * 64 + i * 16 + lrow;
        if (row < M) {
            #pragma unroll
            for (int j = 0; j < 4; ++j) {
                int col = cb + j * 16 + kgrp * 4;
                float4 bb = *(const float4*)(bp + col);
                ushort4 o;
                o.x = f2bf(acc[i][j][0] + bb.x);
                o.y = f2bf(acc[i][j][1] + bb.y);
                o.z = f2bf(acc[i][j][2] + bb.z);
                o.w = f2bf(acc[i][j][3] + bb.w);
                *(ushort4*)(outp + (size_t)row * Nhalf + col) = o;
            }
        }
    }
}

// ---------------- fused GATv2 edge kernel (VEC=8, one wave per node, LDS-free) ----------------
// T = HC/8 lanes per slice, NSL = 64/T slices per wave, pairwise edge loop,
// exp2-domain logits, defer-max rescale, shfl-based cross-slice merge.
template <int HC, int C, bool DO_ELU, bool DO_RES, bool OUT_F32>
__global__ __launch_bounds__(128) void gat_edge8(
        const unsigned short* __restrict__ xl,
        const unsigned short* __restrict__ xr,
        const float* __restrict__ att, const float* __restrict__ bias,
        const unsigned short* __restrict__ res, void* __restrict__ outp,
        const int* __restrict__ row_ptr, const int* __restrict__ csr_src) {
    constexpr int T = HC / 8;      // lanes per slice (32 or 16)
    constexpr int NSL = 64 / T;    // slices per wave (2 or 4)
    constexpr int RW = C / 8;      // lanes per head-reduce group (4 or 16)
    constexpr float THR = 11.54f;  // defer-max threshold (log2 domain, = 8/ln2)

    const int lane = threadIdx.x & 63;
    const int n = __builtin_amdgcn_readfirstlane((blockIdx.x << 1) | (threadIdx.x >> 6));
    const int w = lane / T;        // slice id
    const int t = lane % T;
    const int ch = t * 8;
    const size_t base_r = (size_t)n * HC + ch;

    f32x2 xr2[4], av2[4], acc2[4];
    {
        uint4 u = *(const uint4*)(xr + base_r);
        xr2[0] = f32x2{bflo(u.x), bfhi(u.x)};
        xr2[1] = f32x2{bflo(u.y), bfhi(u.y)};
        xr2[2] = f32x2{bflo(u.z), bfhi(u.z)};
        xr2[3] = f32x2{bflo(u.w), bfhi(u.w)};
        float4 a0 = *(const float4*)(att + ch);
        float4 a1 = *(const float4*)(att + ch + 4);
        av2[0] = f32x2{a0.x, a0.y} * LOG2E;
        av2[1] = f32x2{a0.z, a0.w} * LOG2E;
        av2[2] = f32x2{a1.x, a1.y} * LOG2E;
        av2[3] = f32x2{a1.z, a1.w} * LOG2E;
        #pragma unroll
        for (int qi = 0; qi < 4; ++qi) acc2[qi] = f32x2{0.f, 0.f};
    }

    float m = -1e30f, d = 0.f;
    const int beg = row_ptr[n], end = row_ptr[n + 1];
    int e = beg + w;
    for (; e + NSL < end; e += 2 * NSL) {
        int s0 = csr_src[e], s1 = csr_src[e + NSL];
        uint4 g0 = *(const uint4*)(xl + (size_t)s0 * HC + ch);
        uint4 g1 = *(const uint4*)(xl + (size_t)s1 * HC + ch);
        f32x2 x0[4], x1[4];
        x0[0] = f32x2{bflo(g0.x), bfhi(g0.x)}; x0[1] = f32x2{bflo(g0.y), bfhi(g0.y)};
        x0[2] = f32x2{bflo(g0.z), bfhi(g0.z)}; x0[3] = f32x2{bflo(g0.w), bfhi(g0.w)};
        x1[0] = f32x2{bflo(g1.x), bfhi(g1.x)}; x1[1] = f32x2{bflo(g1.y), bfhi(g1.y)};
        x1[2] = f32x2{bflo(g1.z), bfhi(g1.z)}; x1[3] = f32x2{bflo(g1.w), bfhi(g1.w)};
        f32x2 p02 = {0.f, 0.f}, p12 = {0.f, 0.f};
        #pragma unroll
        for (int qi = 0; qi < 4; ++qi) {
            f32x2 u0 = x0[qi] + xr2[qi];
            f32x2 t0 = u0 * NEG_SLOPE;
            u0.x = fmaxf(u0.x, t0.x); u0.y = fmaxf(u0.y, t0.y);
            p02 = u0 * av2[qi] + p02;
            f32x2 u1 = x1[qi] + xr2[qi];
            f32x2 t1 = u1 * NEG_SLOPE;
            u1.x = fmaxf(u1.x, t1.x); u1.y = fmaxf(u1.y, t1.y);
            p12 = u1 * av2[qi] + p12;
        }
        float p0 = p02.x + p02.y, p1 = p12.x + p12.y;
        #pragma unroll
        for (int mm = RW / 2; mm >= 1; mm >>= 1) {
            p0 += __shfl_xor(p0, mm);
            p1 += __shfl_xor(p1, mm);
        }
        float pmax = fmaxf(p0, p1);
        if (__any(pmax > m + THR)) {
            float mn = fmaxf(m, pmax);
            float sc = exp2f(m - mn);
            float e0 = exp2f(p0 - mn), e1 = exp2f(p1 - mn);
            d = d * sc + e0 + e1;
            f32x2 sc2 = {sc, sc}, e02 = {e0, e0}, e12 = {e1, e1};
            #pragma unroll
            for (int qi = 0; qi < 4; ++qi)
                acc2[qi] = acc2[qi] * sc2 + (x0[qi] * e02 + x1[qi] * e12);
            m = mn;
        } else {
            float e0 = exp2f(p0 - m), e1 = exp2f(p1 - m);
            d += e0 + e1;
            f32x2 e02 = {e0, e0}, e12 = {e1, e1};
            #pragma unroll
            for (int qi = 0; qi < 4; ++qi)
                acc2[qi] = acc2[qi] + (x0[qi] * e02 + x1[qi] * e12);
        }
    }
    if (e < end) {  // tail edge (at most one per slice)
        int s0 = csr_src[e];
        uint4 g0 = *(const uint4*)(xl + (size_t)s0 * HC + ch);
        f32x2 x0[4];
        x0[0] = f32x2{bflo(g0.x), bfhi(g0.x)}; x0[1] = f32x2{bflo(g0.y), bfhi(g0.y)};
        x0[2] = f32x2{bflo(g0.z), bfhi(g0.z)}; x0[3] = f32x2{bflo(g0.w), bfhi(g0.w)};
        f32x2 p02 = {0.f, 0.f};
        #pragma unroll
        for (int qi = 0; qi < 4; ++qi) {
            f32x2 u0 = x0[qi] + xr2[qi];
            f32x2 t0 = u0 * NEG_SLOPE;
            u0.x = fmaxf(u0.x, t0.x); u0.y = fmaxf(u0.y, t0.y);
            p02 = u0 * av2[qi] + p02;
        }
        float p0 = p02.x + p02.y;
        #pragma unroll
        for (int mm = RW / 2; mm >= 1; mm >>= 1) p0 += __shfl_xor(p0, mm);
        if (__any(p0 > m + THR)) {
            float mn = fmaxf(m, p0);
            float sc = exp2f(m - mn);
            float e0 = exp2f(p0 - mn);
            d = d * sc + e0;
            f32x2 sc2 = {sc, sc}, e02 = {e0, e0};
            #pragma unroll
            for (int qi = 0; qi < 4; ++qi) acc2[qi] = acc2[qi] * sc2 + x0[qi] * e02;
            m = mn;
        } else {
            float e0 = exp2f(p0 - m);
            d += e0;
            f32x2 e02 = {e0, e0};
            #pragma unroll
            for (int qi = 0; qi < 4; ++qi) acc2[qi] = acc2[qi] + x0[qi] * e02;
        }
    }

    // cross-slice online-softmax merge via shfl (all in-wave)
    #pragma unroll
    for (int st = T; st < 64; st <<= 1) {
        float mo = __shfl_xor(m, st);
        float do_ = __shfl_xor(d, st);
        float ao[8];
        #pragma unroll
        for (int qi = 0; qi < 4; ++qi) {
            ao[2 * qi]     = __shfl_xor(acc2[qi].x, st);
            ao[2 * qi + 1] = __shfl_xor(acc2[qi].y, st);
        }
        float mn = fmaxf(m, mo);
        float s0 = exp2f(m - mn), s1 = exp2f(mo - mn);
        d = d * s0 + do_ * s1;
        #pragma unroll
        for (int qi = 0; qi < 4; ++qi) {
            acc2[qi].x = acc2[qi].x * s0 + ao[2 * qi] * s1;
            acc2[qi].y = acc2[qi].y * s0 + ao[2 * qi + 1] * s1;
        }
        m = mn;
    }

    if (lane < T) {
        float inv = 1.f / d;  // >=1 edge guaranteed (self loop in slice 0)
        float o[8];
        float4 b0 = *(const float4*)(bias + ch);
        float4 b1 = *(const float4*)(bias + ch + 4);
        o[0] = acc2[0].x * inv + b0.x; o[1] = acc2[0].y * inv + b0.y;
        o[2] = acc2[1].x * inv + b0.z; o[3] = acc2[1].y * inv + b0.w;
        o[4] = acc2[2].x * inv + b1.x; o[5] = acc2[2].y * inv + b1.y;
        o[6] = acc2[3].x * inv + b1.z; o[7] = acc2[3].y * inv + b1.w;
        if constexpr (DO_ELU) {
            #pragma unroll
            for (int v = 0; v < 8; ++v)
                o[v] = o[v] > 0.f ? o[v] : exp2f(o[v] * LOG2E) - 1.f;
        }
        if constexpr (DO_RES) {
            uint4 ru = *(const uint4*)(res + base_r);
            o[0] += bflo(ru.x); o[1] += bfhi(ru.x);
            o[2] += bflo(ru.y); o[3] += bfhi(ru.y);
            o[4] += bflo(ru.z); o[5] += bfhi(ru.z);
            o[6] += bflo(ru.w); o[7] += bfhi(ru.w);
        }
        if constexpr (OUT_F32) {
            float* op = (float*)outp + base_r;
            *(float4*)(op)     = make_float4(o[0], o[1], o[2], o[3]);
            *(float4*)(op + 4) = make_float4(o[4], o[5], o[6], o[7]);
        } else {
            uint4 u;
            u.x = (unsigned)f2bf(o[0]) | ((unsigned)f2bf(o[1]) << 16);
            u.y = (unsigned)f2bf(o[2]) | ((unsigned)f2bf(o[3]) << 16);
            u.z = (unsigned)f2bf(o[4]) | ((unsigned)f2bf(o[5]) << 16);
            u.w = (unsigned)f2bf(o[6]) | ((unsigned)f2bf(o[7]) << 16);
            *(uint4*)((unsigned short*)outp + base_r) = u;
        }
    }
}

// ---------------- host orchestration ----------------
extern "C" void kernel_launch(void* const* d_in, const int* in_sizes, int n_in,
                              void* d_out, int out_size, void* d_ws, size_t ws_size,
                              hipStream_t stream) {
    const float* x  = (const float*)d_in[0];
    const int*   ei = (const int*)d_in[1];
    auto P = [&](int layer, int j) { return (const float*)d_in[2 + 6 * layer + j]; };

    unsigned short* x_bf = (unsigned short*)d_ws;              // [NN][128]
    unsigned short* h0 = x_bf + (size_t)NN * 128;              // [NN][256]
    unsigned short* h1 = h0 + (size_t)NN * 256;                // [NN][256]
    unsigned short* xl = h1 + (size_t)NN * 256;                // [NN][256]
    unsigned short* xr = xl + (size_t)NN * 256;                // [NN][256]
    unsigned short* Wb = xr + (size_t)NN * 256;                // 393216 bf16 (all weights)
    int* csr_src = (int*)(Wb + 393216);                        // [NE2]
    int* row_ptr = csr_src + NE2;
    int* cursor  = row_ptr + (NN + 1);
    int* deg     = cursor + NN;

    // ---- CSR build ----
    hipMemsetAsync(deg, 0, NN * sizeof(int), stream);
    int eb = (NE2 + 255) / 256;
    count_deg<<<eb, 256, 0, stream>>>(ei, deg);
    scan_deg<<<1, 1024, 0, stream>>>(deg, row_ptr, cursor);
    scatter_edges<<<eb, 256, 0, stream>>>(ei, cursor, csr_src);

    // ---- one-shot conversions ----
    conv_weights<<<384, 256, 0, stream>>>(P(0, 0), P(0, 2), P(1, 0), P(1, 2),
                                          P(2, 0), P(2, 2), P(3, 0), P(3, 2), Wb);
    int n4 = NN * 128 / 4;
    f32_to_bf16<<<(n4 + 255) / 256, 256, 0, stream>>>(x, x_bf, n4);

    const int mb = (NN + GBM - 1) / GBM;     // 391
    const int nwgL = 4 * mb, nwgLast = 2 * mb;
    const int gat_g = NN / 2;                // 2 nodes per 128-thread block (1 wave/node)

    // ---- Layer 0: 128 -> 8x32, ELU, no residual ----
    gemm_fused<<<nwgL, 256, 0, stream>>>(x_bf, Wb + 0,      P(0, 1), P(0, 3), xl, xr, NN, 256, 128, 2);
    gat_edge8<256, 32, true, false, false><<<gat_g, 128, 0, stream>>>(xl, xr, P(0, 4), P(0, 5),
                                                                      nullptr, h0, row_ptr, csr_src);
    // ---- Layer 1 ----
    gemm_fused<<<nwgL, 256, 0, stream>>>(h0,   Wb + 65536,  P(1, 1), P(1, 3), xl, xr, NN, 256, 256, 2);
    gat_edge8<256, 32, true, true, false><<<gat_g, 128, 0, stream>>>(xl, xr, P(1, 4), P(1, 5),
                                                                     h0, h1, row_ptr, csr_src);
    // ---- Layer 2 ----
    gemm_fused<<<nwgL, 256, 0, stream>>>(h1,   Wb + 196608, P(2, 1), P(2, 3), xl, xr, NN, 256, 256, 2);
    gat_edge8<256, 32, true, true, false><<<gat_g, 128, 0, stream>>>(xl, xr, P(2, 4), P(2, 5),
                                                                     h1, h0, row_ptr, csr_src);
    // ---- Layer 3: 256 -> 1x128, output fp32 ----
    gemm_fused<<<nwgLast, 256, 0, stream>>>(h0, Wb + 327680, P(3, 1), P(3, 3), xl, xr, NN, 128, 256, 1);
    gat_edge8<128, 128, false, false, true><<<gat_g, 128, 0, stream>>>(xl, xr, P(3, 4), P(3, 5),
                                                                       nullptr, d_out, row_ptr, csr_src);
}

// Round 4
// 395.424 us; speedup vs baseline: 1.1846x; 1.1846x over previous
//
#include <hip/hip_runtime.h>
#include <hip/hip_bf16.h>

// ---------------- problem constants ----------------
constexpr int NN = 50000;     // nodes
constexpr int NE = 400000;    // edges (without self loops)
constexpr int NE2 = NE + NN;  // with self loops
constexpr float NEG_SLOPE = 0.2f;
constexpr float LOG2E = 1.44269504f;

typedef __attribute__((ext_vector_type(8))) __bf16 bf16x8;
typedef __attribute__((ext_vector_type(4))) float f32x4;
typedef __attribute__((ext_vector_type(2))) float f32x2;

__device__ inline float bf2f(unsigned short u) { return __uint_as_float(((unsigned)u) << 16); }
__device__ inline unsigned short f2bf(float f) {
    unsigned x = __float_as_uint(f);
    return (unsigned short)((x + 0x7fffu + ((x >> 16) & 1u)) >> 16);  // RNE
}
__device__ inline float bflo(unsigned u) { return __uint_as_float(u << 16); }
__device__ inline float bfhi(unsigned u) { return __uint_as_float(u & 0xffff0000u); }

__device__ inline void gload16(const unsigned short* g, unsigned short* l) {
    // async global->LDS, 16B per lane; LDS dest is wave-uniform base + lane*16
    __builtin_amdgcn_global_load_lds(
        (const __attribute__((address_space(1))) unsigned int*)(g),
        (__attribute__((address_space(3))) unsigned int*)(l), 16, 0, 0);
}

// ---------------- CSR build ----------------
__global__ void count_deg(const int* __restrict__ ei, int* __restrict__ deg) {
    int e = blockIdx.x * blockDim.x + threadIdx.x;
    if (e >= NE2) return;
    int dst = (e < NE) ? ei[NE + e] : (e - NE);
    atomicAdd(&deg[dst], 1);
}

// multi-block scan: local scan (coalesced, 1 elem/thread) -> block-sum scan -> offset add
constexpr int SCAN_NB = (NN + 1023) / 1024;  // 49

__global__ __launch_bounds__(1024) void scan_local(const int* __restrict__ deg,
                                                   int* __restrict__ row_ptr,
                                                   int* __restrict__ bsum) {
    __shared__ int wsum[16];
    const int t = threadIdx.x, lane = t & 63, w = t >> 6;
    const int i = blockIdx.x * 1024 + t;
    int v = (i < NN) ? deg[i] : 0;
    int x = v;
    #pragma unroll
    for (int off = 1; off < 64; off <<= 1) {
        int y = __shfl_up(x, off);
        if (lane >= off) x += y;
    }
    if (lane == 63) wsum[w] = x;
    __syncthreads();
    if (w == 0 && lane < 16) {
        int s = wsum[lane];
        #pragma unroll
        for (int off = 1; off < 16; off <<= 1) {
            int y = __shfl_up(s, off);
            if (lane >= off) s += y;
        }
        wsum[lane] = s;
    }
    __syncthreads();
    int excl = ((w == 0) ? 0 : wsum[w - 1]) + x - v;  // exclusive within block
    if (i < NN) row_ptr[i] = excl;
    if (t == 1023) bsum[blockIdx.x] = wsum[15];       // block total
}

__global__ void scan_bsums(int* __restrict__ bsum, int* __restrict__ row_ptr) {
    int lane = threadIdx.x;  // 64 threads, single wave
    int v = (lane < SCAN_NB) ? bsum[lane] : 0;
    int x = v;
    #pragma unroll
    for (int off = 1; off < 64; off <<= 1) {
        int y = __shfl_up(x, off);
        if (lane >= off) x += y;
    }
    if (lane < SCAN_NB) bsum[lane] = x - v;  // exclusive block offset
    if (lane == 63) row_ptr[NN] = x;         // grand total (= NE2)
}

__global__ __launch_bounds__(1024) void scan_add(int* __restrict__ row_ptr,
                                                 int* __restrict__ cursor,
                                                 const int* __restrict__ bsum) {
    const int i = blockIdx.x * 1024 + threadIdx.x;
    if (i < NN) {
        int e = row_ptr[i] + bsum[blockIdx.x];
        row_ptr[i] = e;
        cursor[i] = e;
    }
}

__global__ void scatter_edges(const int* __restrict__ ei, int* __restrict__ cursor,
                              int* __restrict__ csr_src) {
    int e = blockIdx.x * blockDim.x + threadIdx.x;
    if (e >= NE2) return;
    int src, dst;
    if (e < NE) { src = ei[e]; dst = ei[NE + e]; }
    else        { src = dst = e - NE; }
    int pos = atomicAdd(&cursor[dst], 1);
    csr_src[pos] = src;
}

// ---------------- fp32 -> bf16 convert (x) ----------------
__global__ void f32_to_bf16(const float* __restrict__ in, unsigned short* __restrict__ out, int n4) {
    int i = blockIdx.x * blockDim.x + threadIdx.x;
    if (i >= n4) return;
    float4 v = *(const float4*)(in + 4 * (size_t)i);
    ushort4 o;
    o.x = f2bf(v.x); o.y = f2bf(v.y); o.z = f2bf(v.z); o.w = f2bf(v.w);
    *(ushort4*)(out + 4 * (size_t)i) = o;
}

// ---------------- one-shot weight conversion: all 8 W matrices -> bf16, concatenated ----------------
__global__ void conv_weights(const float* __restrict__ w0l, const float* __restrict__ w0r,
                             const float* __restrict__ w1l, const float* __restrict__ w1r,
                             const float* __restrict__ w2l, const float* __restrict__ w2r,
                             const float* __restrict__ w3l, const float* __restrict__ w3r,
                             unsigned short* __restrict__ out) {
    int i = blockIdx.x * blockDim.x + threadIdx.x;  // float4 index, 0..98303
    const float* src; int base;
    if      (i < 8192)  { src = w0l; base = 0; }
    else if (i < 16384) { src = w0r; base = 8192; }
    else if (i < 32768) { src = w1l; base = 16384; }
    else if (i < 49152) { src = w1r; base = 32768; }
    else if (i < 65536) { src = w2l; base = 49152; }
    else if (i < 81920) { src = w2r; base = 65536; }
    else if (i < 90112) { src = w3l; base = 81920; }
    else                { src = w3r; base = 90112; }
    float4 v = ((const float4*)src)[i - base];
    ushort4 o;
    o.x = f2bf(v.x); o.y = f2bf(v.y); o.z = f2bf(v.z); o.w = f2bf(v.w);
    ((ushort4*)out)[i] = o;
}

// ---------------- fused bf16 MFMA GEMM: [xl | xr] = A @ [Wl;Wr]^T + bias ----------------
// Single-buffer (R2-proven; 64KB dbuf hit the m132 occupancy cliff). Swapped MFMA
// operands -> lane holds 4 consecutive out-cols -> ushort4 stores. XCD swizzle.
#define GBM 128
#define GBN 128
#define GBK 64

__global__ __launch_bounds__(256) void gemm_fused(const unsigned short* __restrict__ A,
                                                  const unsigned short* __restrict__ Wc,
                                                  const float* __restrict__ bl,
                                                  const float* __restrict__ br,
                                                  unsigned short* __restrict__ outl,
                                                  unsigned short* __restrict__ outr,
                                                  int M, int Nhalf, int K, int lognx) {
    __shared__ __align__(16) unsigned short Alds[GBM * GBK];
    __shared__ __align__(16) unsigned short Wlds[GBN * GBK];
    // bijective XCD swizzle (m204): blocks sharing an A-tile land on the same XCD L2
    const int nwg = gridDim.x;
    const int q = nwg >> 3, r8 = nwg & 7;
    const int xcd = blockIdx.x & 7, off = blockIdx.x >> 3;
    const int wg = (xcd < r8 ? xcd * (q + 1) : r8 * (q + 1) + (xcd - r8) * q) + off;
    const int nx = 1 << lognx;
    const int bm = (wg >> lognx) * GBM, bn = (wg & (nx - 1)) * GBN;

    const int tid = threadIdx.x;
    const int lane = tid & 63, wave = tid >> 6;
    const int wr = wave >> 1, wc = wave & 1;       // wave -> 64x64 sub-tile
    const int lrow = lane & 15, kgrp = lane >> 4;  // fragment indices

    f32x4 acc[4][4] = {};

    for (int k0 = 0; k0 < K; k0 += GBK) {
        // stage A and W: 1024 16B chunks each, 4 per thread, direct to LDS
        #pragma unroll
        for (int i = 0; i < 4; ++i) {
            int p = i * 256 + tid;            // chunk id
            int r = p >> 3, ck = p & 7;       // row, chunk-in-row (8 chunks = 64 bf16)
            int sck = ck ^ (r & 7);           // inverse-swizzled source chunk
            int ga = bm + r; ga = (ga < M) ? ga : (M - 1);   // clamp tail (write-guarded)
            unsigned short* la = &Alds[(unsigned)(i * 256 + wave * 64) * 8];
            gload16(A + (size_t)ga * K + k0 + sck * 8, la);
            unsigned short* lw = &Wlds[(unsigned)(i * 256 + wave * 64) * 8];
            gload16(Wc + (size_t)(bn + r) * K + k0 + sck * 8, lw);
        }
        __syncthreads();
        #pragma unroll
        for (int kk = 0; kk < GBK; kk += 32) {
            bf16x8 av[4], bv[4];
            #pragma unroll
            for (int i = 0; i < 4; ++i) {
                int ar = wr * 64 + i * 16 + lrow;
                int ch = ((kk >> 3) + kgrp) ^ (ar & 7);
                av[i] = *(const bf16x8*)(&Alds[ar * GBK + ch * 8]);
            }
            #pragma unroll
            for (int j = 0; j < 4; ++j) {
                int brw = wc * 64 + j * 16 + lrow;
                int ch = ((kk >> 3) + kgrp) ^ (brw & 7);
                bv[j] = *(const bf16x8*)(&Wlds[brw * GBK + ch * 8]);
            }
            // swapped operands: D row-dim <- bv (out cols), col-dim <- av (out rows)
            #pragma unroll
            for (int i = 0; i < 4; ++i)
                #pragma unroll
                for (int j = 0; j < 4; ++j)
                    acc[i][j] = __builtin_amdgcn_mfma_f32_16x16x32_bf16(bv[j], av[i], acc[i][j], 0, 0, 0);
        }
        __syncthreads();
    }

    // epilogue: lane holds out[row = bm+wr*64+i*16+lrow][col = cb+j*16+kgrp*4+r], r=0..3
    const int half = (bn >= Nhalf) ? 1 : 0;
    unsigned short* outp = half ? outr : outl;
    const float* bp = half ? br : bl;
    const int cb = bn - half * Nhalf + wc * 64;
    #pragma unroll
    for (int i = 0; i < 4; ++i) {
        int row = bm + wr * 64 + i * 16 + lrow;
        if (row < M) {
            #pragma unroll
            for (int j = 0; j < 4; ++j) {
                int col = cb + j * 16 + kgrp * 4;
                float4 bb = *(const float4*)(bp + col);
                ushort4 o;
                o.x = f2bf(acc[i][j][0] + bb.x);
                o.y = f2bf(acc[i][j][1] + bb.y);
                o.z = f2bf(acc[i][j][2] + bb.z);
                o.w = f2bf(acc[i][j][3] + bb.w);
                *(ushort4*)(outp + (size_t)row * Nhalf + col) = o;
            }
        }
    }
}

// ---------------- fused GATv2 edge kernel (VEC=8, one wave per node, LDS-free) ----------------
// T = HC/8 lanes per slice, NSL = 64/T slices per wave, pairwise edge loop,
// exp2-domain logits, defer-max rescale, shfl-based cross-slice merge.
template <int HC, int C, bool DO_ELU, bool DO_RES, bool OUT_F32>
__global__ __launch_bounds__(128) void gat_edge8(
        const unsigned short* __restrict__ xl,
        const unsigned short* __restrict__ xr,
        const float* __restrict__ att, const float* __restrict__ bias,
        const unsigned short* __restrict__ res, void* __restrict__ outp,
        const int* __restrict__ row_ptr, const int* __restrict__ csr_src) {
    constexpr int T = HC / 8;      // lanes per slice (32 or 16)
    constexpr int NSL = 64 / T;    // slices per wave (2 or 4)
    constexpr int RW = C / 8;      // lanes per head-reduce group (4 or 16)
    constexpr float THR = 11.54f;  // defer-max threshold (log2 domain, = 8/ln2)

    const int lane = threadIdx.x & 63;
    const int n = __builtin_amdgcn_readfirstlane((blockIdx.x << 1) | (threadIdx.x >> 6));
    const int w = lane / T;        // slice id
    const int t = lane % T;
    const int ch = t * 8;
    const size_t base_r = (size_t)n * HC + ch;

    f32x2 xr2[4], av2[4], acc2[4];
    {
        uint4 u = *(const uint4*)(xr + base_r);
        xr2[0] = f32x2{bflo(u.x), bfhi(u.x)};
        xr2[1] = f32x2{bflo(u.y), bfhi(u.y)};
        xr2[2] = f32x2{bflo(u.z), bfhi(u.z)};
        xr2[3] = f32x2{bflo(u.w), bfhi(u.w)};
        float4 a0 = *(const float4*)(att + ch);
        float4 a1 = *(const float4*)(att + ch + 4);
        av2[0] = f32x2{a0.x, a0.y} * LOG2E;
        av2[1] = f32x2{a0.z, a0.w} * LOG2E;
        av2[2] = f32x2{a1.x, a1.y} * LOG2E;
        av2[3] = f32x2{a1.z, a1.w} * LOG2E;
        #pragma unroll
        for (int qi = 0; qi < 4; ++qi) acc2[qi] = f32x2{0.f, 0.f};
    }

    float m = -1e30f, d = 0.f;
    const int beg = row_ptr[n], end = row_ptr[n + 1];
    int e = beg + w;
    for (; e + NSL < end; e += 2 * NSL) {
        int s0 = csr_src[e], s1 = csr_src[e + NSL];
        uint4 g0 = *(const uint4*)(xl + (size_t)s0 * HC + ch);
        uint4 g1 = *(const uint4*)(xl + (size_t)s1 * HC + ch);
        f32x2 x0[4], x1[4];
        x0[0] = f32x2{bflo(g0.x), bfhi(g0.x)}; x0[1] = f32x2{bflo(g0.y), bfhi(g0.y)};
        x0[2] = f32x2{bflo(g0.z), bfhi(g0.z)}; x0[3] = f32x2{bflo(g0.w), bfhi(g0.w)};
        x1[0] = f32x2{bflo(g1.x), bfhi(g1.x)}; x1[1] = f32x2{bflo(g1.y), bfhi(g1.y)};
        x1[2] = f32x2{bflo(g1.z), bfhi(g1.z)}; x1[3] = f32x2{bflo(g1.w), bfhi(g1.w)};
        f32x2 p02 = {0.f, 0.f}, p12 = {0.f, 0.f};
        #pragma unroll
        for (int qi = 0; qi < 4; ++qi) {
            f32x2 u0 = x0[qi] + xr2[qi];
            f32x2 t0 = u0 * NEG_SLOPE;
            u0.x = fmaxf(u0.x, t0.x); u0.y = fmaxf(u0.y, t0.y);
            p02 = u0 * av2[qi] + p02;
            f32x2 u1 = x1[qi] + xr2[qi];
            f32x2 t1 = u1 * NEG_SLOPE;
            u1.x = fmaxf(u1.x, t1.x); u1.y = fmaxf(u1.y, t1.y);
            p12 = u1 * av2[qi] + p12;
        }
        float p0 = p02.x + p02.y, p1 = p12.x + p12.y;
        #pragma unroll
        for (int mm = RW / 2; mm >= 1; mm >>= 1) {
            p0 += __shfl_xor(p0, mm);
            p1 += __shfl_xor(p1, mm);
        }
        float pmax = fmaxf(p0, p1);
        if (__any(pmax > m + THR)) {
            float mn = fmaxf(m, pmax);
            float sc = exp2f(m - mn);
            float e0 = exp2f(p0 - mn), e1 = exp2f(p1 - mn);
            d = d * sc + e0 + e1;
            f32x2 sc2 = {sc, sc}, e02 = {e0, e0}, e12 = {e1, e1};
            #pragma unroll
            for (int qi = 0; qi < 4; ++qi)
                acc2[qi] = acc2[qi] * sc2 + (x0[qi] * e02 + x1[qi] * e12);
            m = mn;
        } else {
            float e0 = exp2f(p0 - m), e1 = exp2f(p1 - m);
            d += e0 + e1;
            f32x2 e02 = {e0, e0}, e12 = {e1, e1};
            #pragma unroll
            for (int qi = 0; qi < 4; ++qi)
                acc2[qi] = acc2[qi] + (x0[qi] * e02 + x1[qi] * e12);
        }
    }
    if (e < end) {  // tail edge (at most one per slice)
        int s0 = csr_src[e];
        uint4 g0 = *(const uint4*)(xl + (size_t)s0 * HC + ch);
        f32x2 x0[4];
        x0[0] = f32x2{bflo(g0.x), bfhi(g0.x)}; x0[1] = f32x2{bflo(g0.y), bfhi(g0.y)};
        x0[2] = f32x2{bflo(g0.z), bfhi(g0.z)}; x0[3] = f32x2{bflo(g0.w), bfhi(g0.w)};
        f32x2 p02 = {0.f, 0.f};
        #pragma unroll
        for (int qi = 0; qi < 4; ++qi) {
            f32x2 u0 = x0[qi] + xr2[qi];
            f32x2 t0 = u0 * NEG_SLOPE;
            u0.x = fmaxf(u0.x, t0.x); u0.y = fmaxf(u0.y, t0.y);
            p02 = u0 * av2[qi] + p02;
        }
        float p0 = p02.x + p02.y;
        #pragma unroll
        for (int mm = RW / 2; mm >= 1; mm >>= 1) p0 += __shfl_xor(p0, mm);
        if (__any(p0 > m + THR)) {
            float mn = fmaxf(m, p0);
            float sc = exp2f(m - mn);
            float e0 = exp2f(p0 - mn);
            d = d * sc + e0;
            f32x2 sc2 = {sc, sc}, e02 = {e0, e0};
            #pragma unroll
            for (int qi = 0; qi < 4; ++qi) acc2[qi] = acc2[qi] * sc2 + x0[qi] * e02;
            m = mn;
        } else {
            float e0 = exp2f(p0 - m);
            d += e0;
            f32x2 e02 = {e0, e0};
            #pragma unroll
            for (int qi = 0; qi < 4; ++qi) acc2[qi] = acc2[qi] + x0[qi] * e02;
        }
    }

    // cross-slice online-softmax merge via shfl (all in-wave)
    #pragma unroll
    for (int st = T; st < 64; st <<= 1) {
        float mo = __shfl_xor(m, st);
        float do_ = __shfl_xor(d, st);
        float ao[8];
        #pragma unroll
        for (int qi = 0; qi < 4; ++qi) {
            ao[2 * qi]     = __shfl_xor(acc2[qi].x, st);
            ao[2 * qi + 1] = __shfl_xor(acc2[qi].y, st);
        }
        float mn = fmaxf(m, mo);
        float s0 = exp2f(m - mn), s1 = exp2f(mo - mn);
        d = d * s0 + do_ * s1;
        #pragma unroll
        for (int qi = 0; qi < 4; ++qi) {
            acc2[qi].x = acc2[qi].x * s0 + ao[2 * qi] * s1;
            acc2[qi].y = acc2[qi].y * s0 + ao[2 * qi + 1] * s1;
        }
        m = mn;
    }

    if (lane < T) {
        float inv = 1.f / d;  // >=1 edge guaranteed (self loop in slice 0)
        float o[8];
        float4 b0 = *(const float4*)(bias + ch);
        float4 b1 = *(const float4*)(bias + ch + 4);
        o[0] = acc2[0].x * inv + b0.x; o[1] = acc2[0].y * inv + b0.y;
        o[2] = acc2[1].x * inv + b0.z; o[3] = acc2[1].y * inv + b0.w;
        o[4] = acc2[2].x * inv + b1.x; o[5] = acc2[2].y * inv + b1.y;
        o[6] = acc2[3].x * inv + b1.z; o[7] = acc2[3].y * inv + b1.w;
        if constexpr (DO_ELU) {
            #pragma unroll
            for (int v = 0; v < 8; ++v)
                o[v] = o[v] > 0.f ? o[v] : exp2f(o[v] * LOG2E) - 1.f;
        }
        if constexpr (DO_RES) {
            uint4 ru = *(const uint4*)(res + base_r);
            o[0] += bflo(ru.x); o[1] += bfhi(ru.x);
            o[2] += bflo(ru.y); o[3] += bfhi(ru.y);
            o[4] += bflo(ru.z); o[5] += bfhi(ru.z);
            o[6] += bflo(ru.w); o[7] += bfhi(ru.w);
        }
        if constexpr (OUT_F32) {
            float* op = (float*)outp + base_r;
            *(float4*)(op)     = make_float4(o[0], o[1], o[2], o[3]);
            *(float4*)(op + 4) = make_float4(o[4], o[5], o[6], o[7]);
        } else {
            uint4 u;
            u.x = (unsigned)f2bf(o[0]) | ((unsigned)f2bf(o[1]) << 16);
            u.y = (unsigned)f2bf(o[2]) | ((unsigned)f2bf(o[3]) << 16);
            u.z = (unsigned)f2bf(o[4]) | ((unsigned)f2bf(o[5]) << 16);
            u.w = (unsigned)f2bf(o[6]) | ((unsigned)f2bf(o[7]) << 16);
            *(uint4*)((unsigned short*)outp + base_r) = u;
        }
    }
}

// ---------------- host orchestration ----------------
extern "C" void kernel_launch(void* const* d_in, const int* in_sizes, int n_in,
                              void* d_out, int out_size, void* d_ws, size_t ws_size,
                              hipStream_t stream) {
    const float* x  = (const float*)d_in[0];
    const int*   ei = (const int*)d_in[1];
    auto P = [&](int layer, int j) { return (const float*)d_in[2 + 6 * layer + j]; };

    unsigned short* x_bf = (unsigned short*)d_ws;              // [NN][128]
    unsigned short* h0 = x_bf + (size_t)NN * 128;              // [NN][256]
    unsigned short* h1 = h0 + (size_t)NN * 256;                // [NN][256]
    unsigned short* xl = h1 + (size_t)NN * 256;                // [NN][256]
    unsigned short* xr = xl + (size_t)NN * 256;                // [NN][256]
    unsigned short* Wb = xr + (size_t)NN * 256;                // 393216 bf16 (all weights)
    int* csr_src = (int*)(Wb + 393216);                        // [NE2]
    int* row_ptr = csr_src + NE2;
    int* cursor  = row_ptr + (NN + 1);
    int* deg     = cursor + NN;
    int* bsum    = deg + NN;                                   // [SCAN_NB]

    // ---- CSR build ----
    hipMemsetAsync(deg, 0, NN * sizeof(int), stream);
    int eb = (NE2 + 255) / 256;
    count_deg<<<eb, 256, 0, stream>>>(ei, deg);
    scan_local<<<SCAN_NB, 1024, 0, stream>>>(deg, row_ptr, bsum);
    scan_bsums<<<1, 64, 0, stream>>>(bsum, row_ptr);
    scan_add<<<SCAN_NB, 1024, 0, stream>>>(row_ptr, cursor, bsum);
    scatter_edges<<<eb, 256, 0, stream>>>(ei, cursor, csr_src);

    // ---- one-shot conversions ----
    conv_weights<<<384, 256, 0, stream>>>(P(0, 0), P(0, 2), P(1, 0), P(1, 2),
                                          P(2, 0), P(2, 2), P(3, 0), P(3, 2), Wb);
    int n4 = NN * 128 / 4;
    f32_to_bf16<<<(n4 + 255) / 256, 256, 0, stream>>>(x, x_bf, n4);

    const int mb = (NN + GBM - 1) / GBM;     // 391
    const int nwgL = 4 * mb, nwgLast = 2 * mb;
    const int gat_g = NN / 2;                // 2 nodes per 128-thread block (1 wave/node)

    // ---- Layer 0: 128 -> 8x32, ELU, no residual ----
    gemm_fused<<<nwgL, 256, 0, stream>>>(x_bf, Wb + 0,      P(0, 1), P(0, 3), xl, xr, NN, 256, 128, 2);
    gat_edge8<256, 32, true, false, false><<<gat_g, 128, 0, stream>>>(xl, xr, P(0, 4), P(0, 5),
                                                                      nullptr, h0, row_ptr, csr_src);
    // ---- Layer 1 ----
    gemm_fused<<<nwgL, 256, 0, stream>>>(h0,   Wb + 65536,  P(1, 1), P(1, 3), xl, xr, NN, 256, 256, 2);
    gat_edge8<256, 32, true, true, false><<<gat_g, 128, 0, stream>>>(xl, xr, P(1, 4), P(1, 5),
                                                                     h0, h1, row_ptr, csr_src);
    // ---- Layer 2 ----
    gemm_fused<<<nwgL, 256, 0, stream>>>(h1,   Wb + 196608, P(2, 1), P(2, 3), xl, xr, NN, 256, 256, 2);
    gat_edge8<256, 32, true, true, false><<<gat_g, 128, 0, stream>>>(xl, xr, P(2, 4), P(2, 5),
                                                                     h1, h0, row_ptr, csr_src);
    // ---- Layer 3: 256 -> 1x128, output fp32 ----
    gemm_fused<<<nwgLast, 256, 0, stream>>>(h0, Wb + 327680, P(3, 1), P(3, 3), xl, xr, NN, 128, 256, 1);
    gat_edge8<128, 128, false, false, true><<<gat_g, 128, 0, stream>>>(xl, xr, P(3, 4), P(3, 5),
                                                                       nullptr, d_out, row_ptr, csr_src);
}